// Round 2
// baseline (154.347 us; speedup 1.0000x reference)
//
#include <hip/hip_runtime.h>

#define DIM_IN   8192
#define DIM_OUT  8192
#define FAN      16
#define BATCH    1024
#define NNZ      (DIM_IN * FAN)
#define ROWS     4
#define BLOCK    1024
#define LDS_BYTES (DIM_IN * ROWS * 4)   // 128 KiB
#define NSUB     4
#define SUBCAP   16                      // sub-bucket capacity (<=16 always safe)

// ---------------- generic zero ---------------------------------------------
__global__ void zero_kernel(int* __restrict__ p, int n) {
    int i = blockIdx.x * 1024 + threadIdx.x;
    if (i < n) p[i] = 0;
}

// ---------------- striped scatter (low-contention slot assignment) ---------
// counts2[j*NSUB + sub] chains are ~4 deep instead of 16.
__global__ void scatter_striped_kernel(const int* __restrict__ pre,
                                       const int* __restrict__ post,
                                       int* __restrict__ counts2,
                                       int* __restrict__ tmp) {
    int e = blockIdx.x * 1024 + threadIdx.x;
    if (e < NNZ) {
        int j    = post[e];
        int sub  = e & (NSUB - 1);
        int slot = atomicAdd(&counts2[j * NSUB + sub], 1);
        if (slot < SUBCAP)
            tmp[j * (NSUB * SUBCAP) + sub * SUBCAP + slot] = pre[e];
    }
}

// ---------------- reorder: compact + bank-conflict scheduling --------------
// Bucket each j's 16 indices by LDS bank group g=i&7, then rotate by 2*(j&7):
// at gather step k, the 8 rotation classes of a wave target distinct group
// regions -> ~8 lanes/group (the balanced minimum for 64 lanes / 8 groups).
__global__ __launch_bounds__(256)
void reorder_kernel(const int* __restrict__ tmp,
                    const int* __restrict__ counts2,
                    int* __restrict__ idx) {
    __shared__ int sh [256][16];
    __shared__ int sh2[256][16];
    const int t = threadIdx.x;
    const int j = blockIdx.x * 256 + t;

    // compact the 4 sub-buckets into sh[t][0..15]
    int n = 0;
#pragma unroll
    for (int sub = 0; sub < NSUB; ++sub) {
        int c = counts2[j * NSUB + sub];
        c = c > SUBCAP ? SUBCAP : c;
        const int* src = tmp + j * (NSUB * SUBCAP) + sub * SUBCAP;
        for (int k = 0; k < c; ++k) {
            if (n < 16) sh[t][n] = src[k];
            ++n;
        }
    }
    // pad (problem guarantees n==16; defensive)
    for (int k = n; k < 16; ++k) sh[t][k] = 0;

    // counting-sort by bank group g = i&7 (static unroll; p is a scalar reg)
    int p = 0;
#pragma unroll
    for (int g = 0; g < 8; ++g) {
#pragma unroll
        for (int k = 0; k < 16; ++k) {
            int v = sh[t][k];
            if ((v & 7) == g) sh2[t][p++] = v;
        }
    }

    // rotate by 2*(j&7) and store (coalesced int4 writes)
    const int rot = 2 * (j & 7);
    int4* out = reinterpret_cast<int4*>(idx + (size_t)j * FAN);
#pragma unroll
    for (int q = 0; q < 4; ++q) {
        int4 w;
        w.x = sh2[t][(4 * q + 0 + rot) & 15];
        w.y = sh2[t][(4 * q + 1 + rot) & 15];
        w.z = sh2[t][(4 * q + 2 + rot) & 15];
        w.w = sh2[t][(4 * q + 3 + rot) & 15];
        out[q] = w;
    }
}

// ---------------- fallback direct build (round-1 path, small ws) -----------
__global__ void build_direct_kernel(const int* __restrict__ pre,
                                    const int* __restrict__ post,
                                    int* __restrict__ counts,
                                    int* __restrict__ idx) {
    int e = blockIdx.x * 1024 + threadIdx.x;
    if (e < NNZ) {
        int j = post[e];
        int slot = atomicAdd(&counts[j], 1);
        idx[j * FAN + slot] = pre[e];
    }
}

// ---------------- main gather kernel ---------------------------------------
__global__ __launch_bounds__(BLOCK, 4)
void gather_kernel(const float* __restrict__ x,
                   const int*   __restrict__ idx,
                   float*       __restrict__ y) {
    extern __shared__ float lds[];           // [DIM_IN][ROWS] interleaved
    const int t  = threadIdx.x;
    const int b0 = blockIdx.x * ROWS;

    const float* xr0 = x + (size_t)(b0 + 0) * DIM_IN;
    const float* xr1 = x + (size_t)(b0 + 1) * DIM_IN;
    const float* xr2 = x + (size_t)(b0 + 2) * DIM_IN;
    const float* xr3 = x + (size_t)(b0 + 3) * DIM_IN;
#pragma unroll
    for (int c = 0; c < DIM_IN / BLOCK; ++c) {
        int i = t + c * BLOCK;
        float4 v;
        v.x = xr0[i];
        v.y = xr1[i];
        v.z = xr2[i];
        v.w = xr3[i];
        *reinterpret_cast<float4*>(&lds[i * 4]) = v;
    }
    __syncthreads();

    float* y0 = y + (size_t)(b0 + 0) * DIM_OUT;
    float* y1 = y + (size_t)(b0 + 1) * DIM_OUT;
    float* y2 = y + (size_t)(b0 + 2) * DIM_OUT;
    float* y3 = y + (size_t)(b0 + 3) * DIM_OUT;

#pragma unroll
    for (int o = 0; o < DIM_OUT / BLOCK; ++o) {
        const int j = t + o * BLOCK;
        const int4* ip = reinterpret_cast<const int4*>(idx + (size_t)j * FAN);
        int4 i0 = ip[0];
        int4 i1 = ip[1];
        int4 i2 = ip[2];
        int4 i3 = ip[3];

        float4 acc = make_float4(0.f, 0.f, 0.f, 0.f);
        auto accum = [&](int i) {
            float4 v = *reinterpret_cast<const float4*>(&lds[i * 4]);
            acc.x += v.x; acc.y += v.y; acc.z += v.z; acc.w += v.w;
        };
        accum(i0.x); accum(i0.y); accum(i0.z); accum(i0.w);
        accum(i1.x); accum(i1.y); accum(i1.z); accum(i1.w);
        accum(i2.x); accum(i2.y); accum(i2.z); accum(i2.w);
        accum(i3.x); accum(i3.y); accum(i3.z); accum(i3.w);

        y0[j] = 100.0f * acc.x;
        y1[j] = 100.0f * acc.y;
        y2[j] = 100.0f * acc.z;
        y3[j] = 100.0f * acc.w;
    }
}

// ---------------- launch ---------------------------------------------------
extern "C" void kernel_launch(void* const* d_in, const int* in_sizes, int n_in,
                              void* d_out, int out_size, void* d_ws, size_t ws_size,
                              hipStream_t stream) {
    const float* x    = (const float*)d_in[0];
    const int*   pre  = (const int*)d_in[1];
    const int*   post = (const int*)d_in[2];
    float*       y    = (float*)d_out;

    hipFuncSetAttribute((const void*)gather_kernel,
                        hipFuncAttributeMaxDynamicSharedMemorySize, LDS_BYTES);

    const size_t n_counts2 = DIM_OUT * NSUB;           // 32768
    const size_t n_tmp     = DIM_OUT * NSUB * SUBCAP;  // 524288
    const size_t n_idx     = NNZ;                      // 131072
    const size_t need_striped = (n_counts2 + n_tmp + n_idx) * sizeof(int);

    if (ws_size >= need_striped) {
        int* counts2 = (int*)d_ws;
        int* tmp     = counts2 + n_counts2;
        int* idx     = tmp + n_tmp;

        zero_kernel<<<(int)((n_counts2 + 1023) / 1024), 1024, 0, stream>>>(counts2, (int)n_counts2);
        scatter_striped_kernel<<<NNZ / 1024, 1024, 0, stream>>>(pre, post, counts2, tmp);
        reorder_kernel<<<DIM_OUT / 256, 256, 0, stream>>>(tmp, counts2, idx);
        gather_kernel<<<BATCH / ROWS, BLOCK, LDS_BYTES, stream>>>(x, idx, y);
    } else {
        int* counts = (int*)d_ws;
        int* idx    = counts + DIM_OUT;

        zero_kernel<<<DIM_OUT / 1024, 1024, 0, stream>>>(counts, DIM_OUT);
        build_direct_kernel<<<NNZ / 1024, 1024, 0, stream>>>(pre, post, counts, idx);
        gather_kernel<<<BATCH / ROWS, BLOCK, LDS_BYTES, stream>>>(x, idx, y);
    }
}